// Round 21
// baseline (262.368 us; speedup 1.0000x reference)
//
#include <hip/hip_runtime.h>
#include <hip/hip_bf16.h>
#include <cstdint>
#include <cstddef>

#define SEQ    2048
#define DMODEL 1024
#define DEXP   2048
#define NHEADS 16
#define DHEAD  128

typedef __bf16 bf16x8 __attribute__((ext_vector_type(8)));
typedef float  f32x4  __attribute__((ext_vector_type(4)));

__device__ __forceinline__ unsigned short f2bf(float f) {
  unsigned int u = __builtin_bit_cast(unsigned int, f);
  u = u + 0x7FFFu + ((u >> 16) & 1u);   // round-to-nearest-even
  return (unsigned short)(u >> 16);
}
__device__ __forceinline__ float bf2f(unsigned short h) {
  unsigned int u = ((unsigned int)h) << 16;
  return __builtin_bit_cast(float, u);
}
__device__ __forceinline__ unsigned int pk2bf(float a, float b) {
  return ((unsigned int)f2bf(b) << 16) | f2bf(a);
}

__device__ __forceinline__ void gload_lds16(const void* g, void* l) {
  __builtin_amdgcn_global_load_lds(
      (const __attribute__((address_space(1))) unsigned int*)g,
      (__attribute__((address_space(3))) unsigned int*)l, 16, 0, 0);
}

// ---------------- LayerNorm (one row of 1024 per block; optional 2nd input summed) -------
__global__ __launch_bounds__(256) void ln_kernel(const float* __restrict__ in,
    const float* __restrict__ in2,
    const float* __restrict__ gw, const float* __restrict__ gb,
    unsigned short* __restrict__ out_bf, float* __restrict__ out_f) {
  int row = blockIdx.x, t = threadIdx.x;
  float4 v = reinterpret_cast<const float4*>(in + (size_t)row * DMODEL)[t];
  if (in2) {
    float4 v2 = reinterpret_cast<const float4*>(in2 + (size_t)row * DMODEL)[t];
    v.x += v2.x; v.y += v2.y; v.z += v2.z; v.w += v2.w;
  }
  float s  = v.x + v.y + v.z + v.w;
  float ss = v.x*v.x + v.y*v.y + v.z*v.z + v.w*v.w;
  #pragma unroll
  for (int m = 1; m < 64; m <<= 1) { s += __shfl_xor(s, m, 64); ss += __shfl_xor(ss, m, 64); }
  __shared__ float sh[8];
  if ((t & 63) == 0) { sh[t >> 6] = s; sh[4 + (t >> 6)] = ss; }
  __syncthreads();
  s  = sh[0] + sh[1] + sh[2] + sh[3];
  ss = sh[4] + sh[5] + sh[6] + sh[7];
  float mu  = s * (1.0f / DMODEL);
  float var = ss * (1.0f / DMODEL) - mu * mu;
  float rs  = rsqrtf(var + 1e-5f);
  float4 w4 = reinterpret_cast<const float4*>(gw)[t];
  float4 b4 = reinterpret_cast<const float4*>(gb)[t];
  float o0 = (v.x - mu) * rs * w4.x + b4.x;
  float o1 = (v.y - mu) * rs * w4.y + b4.y;
  float o2 = (v.z - mu) * rs * w4.z + b4.z;
  float o3 = (v.w - mu) * rs * w4.w + b4.w;
  if (out_bf) {
    unsigned short* op = out_bf + (size_t)row * DMODEL + t * 4;
    op[0] = f2bf(o0); op[1] = f2bf(o1); op[2] = f2bf(o2); op[3] = f2bf(o3);
  } else {
    float4 o4; o4.x = o0; o4.y = o1; o4.z = o2; o4.w = o3;
    reinterpret_cast<float4*>(out_f + (size_t)row * DMODEL)[t] = o4;
  }
}

// ---------------- f32 -> bf16 cast, both weights in one launch ----------------
__global__ void castboth(const float* __restrict__ in1, unsigned short* __restrict__ out1,
                         int n1, const float* __restrict__ in2,
                         unsigned short* __restrict__ out2, int n2) {
  int i = blockIdx.x * 256 + threadIdx.x;
  const float* in; unsigned short* out;
  if (i < n1) { in = in1; out = out1; }
  else { i -= n1; if (i >= n2) return; in = in2; out = out2; }
  float4 v = reinterpret_cast<const float4*>(in)[i];
  ushort4 o;
  o.x = f2bf(v.x); o.y = f2bf(v.y); o.z = f2bf(v.z); o.w = f2bf(v.w);
  reinterpret_cast<ushort4*>(out)[i] = o;
}

// ---------------- GEMM v3: BK=64 dbuf + T2 XOR-swizzled LDS (R20-verified) --------------
template<int EPI>
__global__ __launch_bounds__(256) void gemm_lds(
    const unsigned short* __restrict__ A, const unsigned short* __restrict__ B,
    int M, int N, int K,
    const float* __restrict__ b_in, const float* __restrict__ log_scale,
    unsigned short* __restrict__ outq, unsigned short* __restrict__ outk,
    unsigned short* __restrict__ outvt, unsigned short* __restrict__ outp,
    float* __restrict__ outf) {
  int nbn = N / 128;
  int tiles = (M / 128) * nbn;
  int bid = blockIdx.x;
  int part = 0;
  if constexpr (EPI == 1) { part = bid / tiles; bid -= part * tiles; }
  int bm = bid / nbn, bn = bid % nbn;
  int Klen = (EPI == 1) ? (K >> 1) : K;
  int koff = part * Klen;
  int tid = threadIdx.x;
  int wid = tid >> 6, l = tid & 63;
  int wr = wid >> 1, wc = wid & 1;
  int row0 = bm * 128, col0 = bn * 128;
  int c16 = l & 15, g = l >> 4;
  int srow = tid >> 3;
  int sch  = tid & 7;

  __shared__ __align__(16) char SMEM[65536];
  unsigned short* As0 = (unsigned short*)SMEM;            // [2][128*64]
  unsigned short* Bs0 = (unsigned short*)(SMEM + 32768);  // [2][128*64]
  unsigned short* vlds = (unsigned short*)SMEM;           // [128][130] reuse post-K-loop

  f32x4 acc[4][4];
  f32x4 z = {0.f, 0.f, 0.f, 0.f};
  #pragma unroll
  for (int i = 0; i < 4; ++i)
    #pragma unroll
    for (int j = 0; j < 4; ++j) acc[i][j] = z;

  auto STAGE = [&](int b, int kt) {
    int k0 = koff + kt * 64;
    #pragma unroll
    for (int rr = 0; rr < 4; ++rr) {
      int row = rr * 32 + srow;
      int kswz = k0 + ((sch ^ (row & 7)) * 8);   // pre-swizzled global source
      gload_lds16(A + (size_t)(row0 + row) * K + kswz,
                  (char*)(As0 + b * 8192) + rr * 4096 + tid * 16);
      gload_lds16(B + (size_t)(col0 + row) * K + kswz,
                  (char*)(Bs0 + b * 8192) + rr * 4096 + tid * 16);
    }
  };

  int nkt = Klen >> 6;
  STAGE(0, 0);
  __syncthreads();

  for (int kt = 0; kt < nkt; ++kt) {
    int cur = kt & 1;
    if (kt + 1 < nkt) STAGE(cur ^ 1, kt + 1);
    const char* Ab = (const char*)(As0 + cur * 8192);
    const char* Bb = (const char*)(Bs0 + cur * 8192);
    int xo = (c16 & 7) << 4;
    #pragma unroll
    for (int ks = 0; ks < 2; ++ks) {
      bf16x8 a[4], b[4];
      #pragma unroll
      for (int i = 0; i < 4; ++i)
        a[i] = *reinterpret_cast<const bf16x8*>(
            Ab + (wr * 64 + i * 16 + c16) * 128 + ((ks * 64 + g * 16) ^ xo));
      #pragma unroll
      for (int j = 0; j < 4; ++j)
        b[j] = *reinterpret_cast<const bf16x8*>(
            Bb + (wc * 64 + j * 16 + c16) * 128 + ((ks * 64 + g * 16) ^ xo));
      __builtin_amdgcn_s_setprio(1);
      #pragma unroll
      for (int i = 0; i < 4; ++i)
        #pragma unroll
        for (int j = 0; j < 4; ++j)
          acc[i][j] = __builtin_amdgcn_mfma_f32_16x16x32_bf16(a[i], b[j], acc[i][j], 0, 0, 0);
      __builtin_amdgcn_s_setprio(0);
    }
    __syncthreads();
  }

  if constexpr (EPI == 0) {
    int sec = col0 >> 11;               // block-uniform: 0=q 1=k 2=v 3=p
    if (sec == 2) {
      #pragma unroll
      for (int i = 0; i < 4; ++i)
        #pragma unroll
        for (int j = 0; j < 4; ++j)
          #pragma unroll
          for (int r = 0; r < 4; ++r) {
            int lr = wr * 64 + i * 16 + g * 4 + r;
            int lc = wc * 64 + j * 16 + c16;
            vlds[lr * 130 + lc] = f2bf(acc[i][j][r] + b_in[col0 + lc]);
          }
      __syncthreads();
      int colv0 = col0 & 2047;
      int chunk = tid & 15;
      #pragma unroll
      for (int it = 0; it < 8; ++it) {
        int c = it * 16 + (tid >> 4);
        unsigned short tmp[8];
        #pragma unroll
        for (int e = 0; e < 8; ++e) tmp[e] = vlds[(chunk * 8 + e) * 130 + c];
        *reinterpret_cast<uint4*>(outvt + (size_t)(colv0 + c) * SEQ + row0 + chunk * 8) =
            *reinterpret_cast<const uint4*>(tmp);
      }
      return;
    }
  }

  #pragma unroll
  for (int i = 0; i < 4; ++i) {
    #pragma unroll
    for (int j = 0; j < 4; ++j) {
      #pragma unroll
      for (int r = 0; r < 4; ++r) {
        int gi = row0 + wr * 64 + i * 16 + g * 4 + r;
        int n  = col0 + wc * 64 + j * 16 + c16;
        float val = acc[i][j][r];
        if constexpr (EPI == 0) {
          val += b_in[n];
          int sec = n >> 11, nn = n & 2047, hh = nn >> 7;
          if (sec == 0) {
            float qs = __expf(-2.f * log_scale[hh]) * 0.088388347648318447f; // 1/(s^2*sqrt(128))
            outq[(size_t)gi * DEXP + nn] = f2bf(val * qs);
          } else if (sec == 1) {
            outk[(size_t)gi * DEXP + nn] = f2bf(val);
          } else {
            outp[(size_t)gi * DEXP + nn] = f2bf(val);
          }
        } else {
          outf[(size_t)part * M * N + (size_t)gi * N + n] = val;
        }
      }
    }
  }
}

// ---------------- y head ----------------
__global__ __launch_bounds__(256) void yproj(const unsigned short* __restrict__ xn,
    const unsigned short* __restrict__ winbf, const float* __restrict__ b_in,
    float* __restrict__ sig_y) {
  int i = blockIdx.x;
  int t = threadIdx.x, wv = t >> 6, l = t & 63;
  const unsigned short* xr = xn + (size_t)i * DMODEL;
  for (int h = wv; h < NHEADS; h += 4) {
    const unsigned short* wr = winbf + (size_t)(4 * DEXP + h) * DMODEL;
    float s = 0.f;
    #pragma unroll
    for (int e = 0; e < 16; ++e) {
      int idx = l + 64 * e;
      s += bf2f(xr[idx]) * bf2f(wr[idx]);
    }
    #pragma unroll
    for (int m = 1; m < 64; m <<= 1) s += __shfl_xor(s, m, 64);
    if (l == 0) {
      float yv = s + b_in[4 * DEXP + h];
      sig_y[h * SEQ + i] = 1.f / (1.f + __expf(-yv));
    }
  }
}

// ---------------- inclusive scan of sig_y per head -> pos[h][i] ----------------
__global__ __launch_bounds__(256) void scan_kernel(const float* __restrict__ sig_y,
                                                   float* __restrict__ pos) {
  int h = blockIdx.x, t = threadIdx.x;
  const float* in = sig_y + (size_t)h * SEQ;
  float v[8], s = 0.f;
  #pragma unroll
  for (int e = 0; e < 8; ++e) { v[e] = in[t * 8 + e]; s += v[e]; }
  __shared__ float sh[256];
  sh[t] = s;
  __syncthreads();
  for (int off = 1; off < 256; off <<= 1) {
    float add = (t >= off) ? sh[t - off] : 0.f;
    __syncthreads();
    sh[t] += add;
    __syncthreads();
  }
  float run = sh[t] - s;
  float* op = pos + (size_t)h * SEQ;
  #pragma unroll
  for (int e = 0; e < 8; ++e) { run += v[e]; op[t * 8 + e] = run; }
}

// ---------------- smear ----------------
__global__ void smear_kernel(const unsigned short* __restrict__ projk,
    const float* __restrict__ smearf, unsigned short* __restrict__ ksm) {
  int idx = blockIdx.x * 256 + threadIdx.x;
  if (idx >= SEQ * DEXP) return;
  int i = idx >> 11, nn = idx & 2047, h = nn >> 7;
  float sf = 1.f / (1.f + __expf(-smearf[h]));
  float kc = bf2f(projk[idx]);
  float kp = (i > 0) ? bf2f(projk[idx - DEXP]) : 0.f;
  ksm[idx] = f2bf((1.f - sf) * kc + sf * kp);
}

// ---------------- flash attention v10: 4-way j-split, 32 waves/CU -----------------------
// 512 blocks x 1024 threads (16 waves): 4 q-groups (w4, 16 rows) x 4 j-quarters (jq, 16
// j-cols). 2 blocks/CU = 32 waves/CU (2x R15's TLP). PV keeps the verified K=32 MFMA by
// ZERO-PADDING P^T slots k=16..31 (g>=2 lanes: pb=0; V read clamped via g&1 to valid
// memory, product exactly 0). Same shuffle formula src = c16 + ((g&1)<<5). 3-round tree
// merge of (m,l,O) through dead staging LDS. Defer-max + defer-psum kept.
__global__ __launch_bounds__(1024, 8) void attn_kernel(
    const unsigned short* __restrict__ q, const unsigned short* __restrict__ ksm,
    const unsigned short* __restrict__ vt, const unsigned short* __restrict__ projp,
    const float* __restrict__ pos, unsigned short* __restrict__ ap) {
  int bid = blockIdx.x;
  int swz = (bid & 7) * 64 + (bid >> 3);   // bijective XCD swizzle: 2 heads per XCD
  int h = swz >> 5;
  int low5 = swz & 31;
  int qc = (h & 1) ? (31 - low5) : low5;   // complementary lengths for co-resident pair
  int q0 = qc * 64;
  int tid = threadIdx.x;
  int wid = tid >> 6, l = tid & 63;
  int w4 = wid & 3, jq = wid >> 2;         // q-group, j-quarter (0..3)
  int joff = jq * 16;
  int c16 = l & 15, g = l >> 4;

  __shared__ __align__(16) char SMEMa[65536];
  // staging: K[b] at b*16384 ([64][256B]); V[b] at 32768 + b*16384 ([128][128B])

  int qrow = q0 + w4 * 16 + c16;
  int wmax = q0 + w4 * 16 + 15;
  bf16x8 qf[4];
  {
    const unsigned short* qb = q + (size_t)qrow * DEXP + h * DHEAD + g * 8;
    #pragma unroll
    for (int f = 0; f < 4; ++f) qf[f] = *reinterpret_cast<const bf16x8*>(qb + f * 32);
  }
  float pos_q = pos[h * SEQ + qrow];
  float m_run = -1e30f, l_run = 0.f;       // per-lane partial l (defer-psum)
  f32x4 z = {0.f, 0.f, 0.f, 0.f};
  f32x4 oacc[8];
  #pragma unroll
  for (int d = 0; d < 8; ++d) oacc[d] = z;

  int ntiles = qc + 1;
  int kch = tid & 15;                      // K: 16 chunks x 64 rows = 1024 threads
  int vch = tid & 7;                       // V: 8 chunks x 128 rows = 1024 threads

  auto STAGE = [&](int b, int t) {
    int j0 = t * 64;
    {
      int row = tid >> 4;   // 0..63
      gload_lds16(ksm + (size_t)(j0 + row) * DEXP + h * DHEAD + ((kch ^ (row & 7)) * 8),
                  SMEMa + b * 16384 + tid * 16);
    }
    {
      int row = tid >> 3;   // 0..127
      gload_lds16(vt + (size_t)(h * DHEAD + row) * SEQ + j0 + ((vch ^ (row & 7)) * 8),
                  SMEMa + 32768 + b * 16384 + tid * 16);
    }
  };

  STAGE(0, 0);
  __syncthreads();

  for (int t = 0; t < ntiles; ++t) {
    int cur = t & 1;
    if (t + 1 < ntiles) STAGE(cur ^ 1, t + 1);
    int j0 = t * 64;
    if (j0 + joff <= wmax) {   // wave-uniform skip of fully-masked quarter-tiles
      const char* Kb = SMEMa + cur * 16384;
      const char* Vb = SMEMa + 32768 + cur * 16384;
      // ---- QK^T (swapped) on this wave's 16 j-columns ----
      f32x4 sT = z;
      const char* kb = Kb + (joff + c16) * 256;
      __builtin_amdgcn_s_setprio(1);
      #pragma unroll
      for (int f = 0; f < 4; ++f) {
        int cb = (f * 64 + g * 16) ^ ((c16 & 7) << 4);
        bf16x8 kf = *reinterpret_cast<const bf16x8*>(kb + cb);
        sT = __builtin_amdgcn_mfma_f32_16x16x32_bf16(kf, qf[f], sT, 0, 0, 0);
      }
      __builtin_amdgcn_s_setprio(0);
      // ---- mask + lane-local online softmax (defer-max, defer-psum) ----
      float a4[4], mt = -1e30f;
      float4 pjv = *reinterpret_cast<const float4*>(pos + h * SEQ + j0 + joff + g * 4);
      float pj4[4] = { pjv.x, pjv.y, pjv.z, pjv.w };
      #pragma unroll
      for (int r = 0; r < 4; ++r) {
        int j = j0 + joff + g * 4 + r;
        a4[r] = sT[r] - pos_q + pj4[r] + (j > qrow ? -1e10f : 0.f);
        mt = fmaxf(mt, a4[r]);
      }
      mt = fmaxf(mt, __shfl_xor(mt, 16, 64));
      mt = fmaxf(mt, __shfl_xor(mt, 32, 64));
      float mn = fmaxf(m_run, mt);
      if (mn - m_run > 8.f) {
        float alpha = __expf(m_run - mn);
        l_run *= alpha;
        #pragma unroll
        for (int d = 0; d < 8; ++d)
          #pragma unroll
          for (int r = 0; r < 4; ++r) oacc[d][r] *= alpha;
        m_run = mn;
      }
      float p4[4];
      #pragma unroll
      for (int r = 0; r < 4; ++r) { p4[r] = __expf(a4[r] - m_run); l_run += p4[r]; }
      // ---- P^T B-fragment: k=0..15 real (j-local), k=16..31 ZERO (g>=2) ----
      unsigned long long pk = ((unsigned long long)pk2bf(p4[2], p4[3]) << 32)
                            |  pk2bf(p4[0], p4[1]);
      int src = c16 + ((g & 1) << 5);
      unsigned long long u0 = __shfl(pk, src, 64);
      unsigned long long u1 = __shfl(pk, src + 16, 64);
      union { unsigned long long u[2]; bf16x8 v; } pb;
      pb.u[0] = (g < 2) ? u0 : 0ull;
      pb.u[1] = (g < 2) ? u1 : 0ull;
      // ---- PV (swapped, K=32 zero-padded): one MFMA per d ----
      int gg = g & 1;   // g>=2 reads same bytes as g-2 (valid memory; x0 anyway)
      #pragma unroll
      for (int d = 0; d < 8; ++d) {
        const char* vb = Vb + (d * 16 + c16) * 128;
        int cb = (joff * 2 + gg * 16) ^ ((c16 & 7) << 4);
        bf16x8 vf = *reinterpret_cast<const bf16x8*>(vb + cb);
        __builtin_amdgcn_s_setprio(1);
        oacc[d] = __builtin_amdgcn_mfma_f32_16x16x32_bf16(vf, pb.v, oacc[d], 0, 0, 0);
        __builtin_amdgcn_s_setprio(0);
      }
    }
    __syncthreads();
  }

  // ---- in-wave reduce of deferred l partials ----
  l_run += __shfl_xor(l_run, 16, 64);
  l_run += __shfl_xor(l_run, 32, 64);
  __syncthreads();   // staging buffers dead from here

  float* obuf = (float*)SMEMa;                  // [4 q-groups][16 rows][132]
  float* mbuf = (float*)(SMEMa + 33792);        // [4][2][16]

  auto WRITE = [&]() {
    if (g == 0) {
      mbuf[(w4 * 2 + 0) * 16 + c16] = m_run;
      mbuf[(w4 * 2 + 1) * 16 + c16] = l_run;
    }
    #pragma unroll
    for (int d = 0; d < 8; ++d)
      #pragma unroll
      for (int r = 0; r < 4; ++r)
        obuf[(w4 * 16 + c16) * 132 + d * 16 + g * 4 + r] = oacc[d][r];
  };
  auto MERGE = [&]() {
    float mB = mbuf[(w4 * 2 + 0) * 16 + c16];
    float lB = mbuf[(w4 * 2 + 1) * 16 + c16];
    float M = fmaxf(m_run, mB);
    float sA = __expf(m_run - M), sB = __expf(mB - M);
    #pragma unroll
    for (int d = 0; d < 8; ++d)
      #pragma unroll
      for (int r = 0; r < 4; ++r)
        oacc[d][r] = oacc[d][r] * sA + obuf[(w4 * 16 + c16) * 132 + d * 16 + g * 4 + r] * sB;
    l_run = l_run * sA + lB * sB;
    m_run = M;
  };

  if (jq == 1) WRITE();
  __syncthreads();
  if (jq == 0) MERGE();
  __syncthreads();
  if (jq == 3) WRITE();
  __syncthreads();
  if (jq == 2) MERGE();
  __syncthreads();
  if (jq == 2) WRITE();
  __syncthreads();
  if (jq == 0) {
    MERGE();
    float inv_l = 1.0f / l_run;
    #pragma unroll
    for (int d = 0; d < 8; ++d) {
      int nn = h * DHEAD + d * 16 + g * 4;
      ushort4 pv4 = *reinterpret_cast<const ushort4*>(projp + (size_t)qrow * DEXP + nn);
      ushort4 o4;
      unsigned short* pvp = reinterpret_cast<unsigned short*>(&pv4);
      unsigned short* op  = reinterpret_cast<unsigned short*>(&o4);
      #pragma unroll
      for (int r = 0; r < 4; ++r) {
        float o = oacc[d][r] * inv_l;
        float pv = bf2f(pvp[r]);
        float si = pv / (1.f + __expf(-pv));
        op[r] = f2bf(si * o);
      }
      *reinterpret_cast<ushort4*>(ap + (size_t)qrow * DEXP + nn) = o4;
    }
  }
}

extern "C" void kernel_launch(void* const* d_in, const int* in_sizes, int n_in,
                              void* d_out, int out_size, void* d_ws, size_t ws_size,
                              hipStream_t stream) {
  const float* x         = (const float*)d_in[0];
  const float* W_in      = (const float*)d_in[1];
  const float* b_in      = (const float*)d_in[2];
  const float* in_ln_w   = (const float*)d_in[3];
  const float* in_ln_b   = (const float*)d_in[4];
  const float* W_out     = (const float*)d_in[5];
  const float* out_ln_w  = (const float*)d_in[6];
  const float* out_ln_b  = (const float*)d_in[7];
  const float* smearf    = (const float*)d_in[8];
  const float* log_scale = (const float*)d_in[9];
  float* out = (float*)d_out;

  char* ws = (char*)d_ws;
  size_t off = 0;
  auto alloc = [&](size_t bytes) -> void* {
    void* p = ws + off;
    off += (bytes + 255) & ~(size_t)255;
    return p;
  };
  unsigned short* xn     = (unsigned short*)alloc((size_t)SEQ * DMODEL * 2);
  unsigned short* winbf  = (unsigned short*)alloc((size_t)(4 * DEXP + NHEADS) * DMODEL * 2);
  unsigned short* woutbf = (unsigned short*)alloc((size_t)DMODEL * DEXP * 2);
  unsigned short* projq  = (unsigned short*)alloc((size_t)SEQ * DEXP * 2);
  unsigned short* projk  = (unsigned short*)alloc((size_t)SEQ * DEXP * 2);
  unsigned short* projp  = (unsigned short*)alloc((size_t)SEQ * DEXP * 2);
  unsigned short* vtb    = (unsigned short*)alloc((size_t)SEQ * DEXP * 2);
  unsigned short* ksm    = (unsigned short*)alloc((size_t)SEQ * DEXP * 2);
  unsigned short* apb    = (unsigned short*)alloc((size_t)SEQ * DEXP * 2);
  float* sig_y = (float*)alloc((size_t)NHEADS * SEQ * 4);
  float* posb  = (float*)alloc((size_t)NHEADS * SEQ * 4);
  float* outf  = (float*)alloc((size_t)2 * SEQ * DMODEL * 4);   // 2 split-K partials

  int nwin4  = (4 * DEXP + NHEADS) * DMODEL / 4;
  int nwout4 = DMODEL * DEXP / 4;
  castboth<<<(nwin4 + nwout4 + 255) / 256, 256, 0, stream>>>(
      W_in, winbf, nwin4, W_out, woutbf, nwout4);
  ln_kernel<<<SEQ, 256, 0, stream>>>(x, nullptr, in_ln_w, in_ln_b, xn, nullptr);
  gemm_lds<0><<<(SEQ / 128) * (4 * DEXP / 128), 256, 0, stream>>>(
      xn, winbf, SEQ, 4 * DEXP, DMODEL, b_in, log_scale, projq, projk, vtb, projp, nullptr);
  yproj<<<SEQ, 256, 0, stream>>>(xn, winbf, b_in, sig_y);
  scan_kernel<<<NHEADS, 256, 0, stream>>>(sig_y, posb);
  smear_kernel<<<(SEQ * DEXP + 255) / 256, 256, 0, stream>>>(projk, smearf, ksm);
  attn_kernel<<<512, 1024, 0, stream>>>(projq, ksm, vtb, projp, posb, apb);
  gemm_lds<1><<<2 * (SEQ / 128) * (DMODEL / 128), 256, 0, stream>>>(
      apb, woutbf, SEQ, DMODEL, DEXP, nullptr, nullptr, nullptr, nullptr, nullptr, nullptr, outf);
  ln_kernel<<<SEQ, 256, 0, stream>>>(outf, outf + (size_t)SEQ * DMODEL, out_ln_w, out_ln_b,
                                     nullptr, out);
}

// Round 22
// 164.803 us; speedup vs baseline: 1.5920x; 1.5920x over previous
//
#include <hip/hip_runtime.h>
#include <hip/hip_bf16.h>
#include <cstdint>
#include <cstddef>

#define SEQ    2048
#define DMODEL 1024
#define DEXP   2048
#define NHEADS 16
#define DHEAD  128

typedef __bf16 bf16x8 __attribute__((ext_vector_type(8)));
typedef float  f32x4  __attribute__((ext_vector_type(4)));

__device__ __forceinline__ unsigned short f2bf(float f) {
  unsigned int u = __builtin_bit_cast(unsigned int, f);
  u = u + 0x7FFFu + ((u >> 16) & 1u);   // round-to-nearest-even
  return (unsigned short)(u >> 16);
}
__device__ __forceinline__ float bf2f(unsigned short h) {
  unsigned int u = ((unsigned int)h) << 16;
  return __builtin_bit_cast(float, u);
}
__device__ __forceinline__ unsigned int pk2bf(float a, float b) {
  return ((unsigned int)f2bf(b) << 16) | f2bf(a);
}

__device__ __forceinline__ void gload_lds16(const void* g, void* l) {
  __builtin_amdgcn_global_load_lds(
      (const __attribute__((address_space(1))) unsigned int*)g,
      (__attribute__((address_space(3))) unsigned int*)l, 16, 0, 0);
}

// ---------------- LayerNorm (one row of 1024 per block; optional 2nd input summed) -------
__global__ __launch_bounds__(256) void ln_kernel(const float* __restrict__ in,
    const float* __restrict__ in2,
    const float* __restrict__ gw, const float* __restrict__ gb,
    unsigned short* __restrict__ out_bf, float* __restrict__ out_f) {
  int row = blockIdx.x, t = threadIdx.x;
  float4 v = reinterpret_cast<const float4*>(in + (size_t)row * DMODEL)[t];
  if (in2) {
    float4 v2 = reinterpret_cast<const float4*>(in2 + (size_t)row * DMODEL)[t];
    v.x += v2.x; v.y += v2.y; v.z += v2.z; v.w += v2.w;
  }
  float s  = v.x + v.y + v.z + v.w;
  float ss = v.x*v.x + v.y*v.y + v.z*v.z + v.w*v.w;
  #pragma unroll
  for (int m = 1; m < 64; m <<= 1) { s += __shfl_xor(s, m, 64); ss += __shfl_xor(ss, m, 64); }
  __shared__ float sh[8];
  if ((t & 63) == 0) { sh[t >> 6] = s; sh[4 + (t >> 6)] = ss; }
  __syncthreads();
  s  = sh[0] + sh[1] + sh[2] + sh[3];
  ss = sh[4] + sh[5] + sh[6] + sh[7];
  float mu  = s * (1.0f / DMODEL);
  float var = ss * (1.0f / DMODEL) - mu * mu;
  float rs  = rsqrtf(var + 1e-5f);
  float4 w4 = reinterpret_cast<const float4*>(gw)[t];
  float4 b4 = reinterpret_cast<const float4*>(gb)[t];
  float o0 = (v.x - mu) * rs * w4.x + b4.x;
  float o1 = (v.y - mu) * rs * w4.y + b4.y;
  float o2 = (v.z - mu) * rs * w4.z + b4.z;
  float o3 = (v.w - mu) * rs * w4.w + b4.w;
  if (out_bf) {
    unsigned short* op = out_bf + (size_t)row * DMODEL + t * 4;
    op[0] = f2bf(o0); op[1] = f2bf(o1); op[2] = f2bf(o2); op[3] = f2bf(o3);
  } else {
    float4 o4; o4.x = o0; o4.y = o1; o4.z = o2; o4.w = o3;
    reinterpret_cast<float4*>(out_f + (size_t)row * DMODEL)[t] = o4;
  }
}

// ---------------- f32 -> bf16 cast, both weights in one launch ----------------
__global__ void castboth(const float* __restrict__ in1, unsigned short* __restrict__ out1,
                         int n1, const float* __restrict__ in2,
                         unsigned short* __restrict__ out2, int n2) {
  int i = blockIdx.x * 256 + threadIdx.x;
  const float* in; unsigned short* out;
  if (i < n1) { in = in1; out = out1; }
  else { i -= n1; if (i >= n2) return; in = in2; out = out2; }
  float4 v = reinterpret_cast<const float4*>(in)[i];
  ushort4 o;
  o.x = f2bf(v.x); o.y = f2bf(v.y); o.z = f2bf(v.z); o.w = f2bf(v.w);
  reinterpret_cast<ushort4*>(out)[i] = o;
}

// ---------------- GEMM v3: BK=64 dbuf + T2 XOR-swizzled LDS ------------------------------
template<int EPI>
__global__ __launch_bounds__(256) void gemm_lds(
    const unsigned short* __restrict__ A, const unsigned short* __restrict__ B,
    int M, int N, int K,
    const float* __restrict__ b_in, const float* __restrict__ log_scale,
    unsigned short* __restrict__ outq, unsigned short* __restrict__ outk,
    unsigned short* __restrict__ outvt, unsigned short* __restrict__ outp,
    float* __restrict__ outf) {
  int nbn = N / 128;
  int tiles = (M / 128) * nbn;
  int bid = blockIdx.x;
  int part = 0;
  if constexpr (EPI == 1) { part = bid / tiles; bid -= part * tiles; }
  int bm = bid / nbn, bn = bid % nbn;
  int Klen = (EPI == 1) ? (K >> 1) : K;
  int koff = part * Klen;
  int tid = threadIdx.x;
  int wid = tid >> 6, l = tid & 63;
  int wr = wid >> 1, wc = wid & 1;
  int row0 = bm * 128, col0 = bn * 128;
  int c16 = l & 15, g = l >> 4;
  int srow = tid >> 3;          // staging row 0..31 per rr-round
  int sch  = tid & 7;           // staging 16B-chunk position within 128B row

  __shared__ __align__(16) char SMEM[65536];
  unsigned short* As0 = (unsigned short*)SMEM;            // [2][128*64]
  unsigned short* Bs0 = (unsigned short*)(SMEM + 32768);  // [2][128*64]
  unsigned short* vlds = (unsigned short*)SMEM;           // [128][130] reuse post-K-loop

  f32x4 acc[4][4];
  f32x4 z = {0.f, 0.f, 0.f, 0.f};
  #pragma unroll
  for (int i = 0; i < 4; ++i)
    #pragma unroll
    for (int j = 0; j < 4; ++j) acc[i][j] = z;

  auto STAGE = [&](int b, int kt) {
    int k0 = koff + kt * 64;
    #pragma unroll
    for (int rr = 0; rr < 4; ++rr) {
      int row = rr * 32 + srow;
      int kswz = k0 + ((sch ^ (row & 7)) * 8);   // pre-swizzled global source
      gload_lds16(A + (size_t)(row0 + row) * K + kswz,
                  (char*)(As0 + b * 8192) + rr * 4096 + tid * 16);
      gload_lds16(B + (size_t)(col0 + row) * K + kswz,
                  (char*)(Bs0 + b * 8192) + rr * 4096 + tid * 16);
    }
  };

  int nkt = Klen >> 6;
  STAGE(0, 0);
  __syncthreads();   // vmcnt drained -> tile 0 visible

  for (int kt = 0; kt < nkt; ++kt) {
    int cur = kt & 1;
    if (kt + 1 < nkt) STAGE(cur ^ 1, kt + 1);   // prefetch lands under compute
    const char* Ab = (const char*)(As0 + cur * 8192);
    const char* Bb = (const char*)(Bs0 + cur * 8192);
    int xo = (c16 & 7) << 4;                     // read-side XOR (row&7 == c16&7)
    #pragma unroll
    for (int ks = 0; ks < 2; ++ks) {
      bf16x8 a[4], b[4];
      #pragma unroll
      for (int i = 0; i < 4; ++i)
        a[i] = *reinterpret_cast<const bf16x8*>(
            Ab + (wr * 64 + i * 16 + c16) * 128 + ((ks * 64 + g * 16) ^ xo));
      #pragma unroll
      for (int j = 0; j < 4; ++j)
        b[j] = *reinterpret_cast<const bf16x8*>(
            Bb + (wc * 64 + j * 16 + c16) * 128 + ((ks * 64 + g * 16) ^ xo));
      __builtin_amdgcn_s_setprio(1);
      #pragma unroll
      for (int i = 0; i < 4; ++i)
        #pragma unroll
        for (int j = 0; j < 4; ++j)
          acc[i][j] = __builtin_amdgcn_mfma_f32_16x16x32_bf16(a[i], b[j], acc[i][j], 0, 0, 0);
      __builtin_amdgcn_s_setprio(0);
    }
    __syncthreads();   // prefetch complete; cur free for kt+2's stage
  }

  if constexpr (EPI == 0) {
    int sec = col0 >> 11;               // block-uniform: 0=q 1=k 2=v 3=p
    if (sec == 2) {
      // ---- v section: bias, cast, LDS transpose, coalesced vt write ----
      #pragma unroll
      for (int i = 0; i < 4; ++i)
        #pragma unroll
        for (int j = 0; j < 4; ++j)
          #pragma unroll
          for (int r = 0; r < 4; ++r) {
            int lr = wr * 64 + i * 16 + g * 4 + r;
            int lc = wc * 64 + j * 16 + c16;
            vlds[lr * 130 + lc] = f2bf(acc[i][j][r] + b_in[col0 + lc]);
          }
      __syncthreads();
      int colv0 = col0 & 2047;
      int chunk = tid & 15;
      #pragma unroll
      for (int it = 0; it < 8; ++it) {
        int c = it * 16 + (tid >> 4);
        unsigned short tmp[8];
        #pragma unroll
        for (int e = 0; e < 8; ++e) tmp[e] = vlds[(chunk * 8 + e) * 130 + c];
        *reinterpret_cast<uint4*>(outvt + (size_t)(colv0 + c) * SEQ + row0 + chunk * 8) =
            *reinterpret_cast<const uint4*>(tmp);
      }
      return;
    }
  }

  #pragma unroll
  for (int i = 0; i < 4; ++i) {
    #pragma unroll
    for (int j = 0; j < 4; ++j) {
      #pragma unroll
      for (int r = 0; r < 4; ++r) {
        int gi = row0 + wr * 64 + i * 16 + g * 4 + r;
        int n  = col0 + wc * 64 + j * 16 + c16;
        float val = acc[i][j][r];
        if constexpr (EPI == 0) {
          val += b_in[n];
          int sec = n >> 11, nn = n & 2047, hh = nn >> 7;
          if (sec == 0) {
            float qs = __expf(-2.f * log_scale[hh]) * 0.088388347648318447f; // 1/(s^2*sqrt(128))
            outq[(size_t)gi * DEXP + nn] = f2bf(val * qs);
          } else if (sec == 1) {
            outk[(size_t)gi * DEXP + nn] = f2bf(val);
          } else {
            outp[(size_t)gi * DEXP + nn] = f2bf(val);
          }
        } else {
          outf[(size_t)part * M * N + (size_t)gi * N + n] = val;
        }
      }
    }
  }
}

// ---------------- y head ----------------
__global__ __launch_bounds__(256) void yproj(const unsigned short* __restrict__ xn,
    const unsigned short* __restrict__ winbf, const float* __restrict__ b_in,
    float* __restrict__ sig_y) {
  int i = blockIdx.x;
  int t = threadIdx.x, wv = t >> 6, l = t & 63;
  const unsigned short* xr = xn + (size_t)i * DMODEL;
  for (int h = wv; h < NHEADS; h += 4) {
    const unsigned short* wr = winbf + (size_t)(4 * DEXP + h) * DMODEL;
    float s = 0.f;
    #pragma unroll
    for (int e = 0; e < 16; ++e) {
      int idx = l + 64 * e;
      s += bf2f(xr[idx]) * bf2f(wr[idx]);
    }
    #pragma unroll
    for (int m = 1; m < 64; m <<= 1) s += __shfl_xor(s, m, 64);
    if (l == 0) {
      float yv = s + b_in[4 * DEXP + h];
      sig_y[h * SEQ + i] = 1.f / (1.f + __expf(-yv));
    }
  }
}

// ---------------- inclusive scan of sig_y per head -> pos[h][i] ----------------
__global__ __launch_bounds__(256) void scan_kernel(const float* __restrict__ sig_y,
                                                   float* __restrict__ pos) {
  int h = blockIdx.x, t = threadIdx.x;
  const float* in = sig_y + (size_t)h * SEQ;
  float v[8], s = 0.f;
  #pragma unroll
  for (int e = 0; e < 8; ++e) { v[e] = in[t * 8 + e]; s += v[e]; }
  __shared__ float sh[256];
  sh[t] = s;
  __syncthreads();
  for (int off = 1; off < 256; off <<= 1) {
    float add = (t >= off) ? sh[t - off] : 0.f;
    __syncthreads();
    sh[t] += add;
    __syncthreads();
  }
  float run = sh[t] - s;
  float* op = pos + (size_t)h * SEQ;
  #pragma unroll
  for (int e = 0; e < 8; ++e) { run += v[e]; op[t * 8 + e] = run; }
}

// ---------------- smear ----------------
__global__ void smear_kernel(const unsigned short* __restrict__ projk,
    const float* __restrict__ smearf, unsigned short* __restrict__ ksm) {
  int idx = blockIdx.x * 256 + threadIdx.x;
  if (idx >= SEQ * DEXP) return;
  int i = idx >> 11, nn = idx & 2047, h = nn >> 7;
  float sf = 1.f / (1.f + __expf(-smearf[h]));
  float kc = bf2f(projk[idx]);
  float kp = (i > 0) ? bf2f(projk[idx - DEXP]) : 0.f;
  ksm[idx] = f2bf((1.f - sf) * kc + sf * kp);
}

// ---------------- flash attention v9 (R19-measured best): j-split wave pairs ------------
__global__ __launch_bounds__(512) void attn_kernel(
    const unsigned short* __restrict__ q, const unsigned short* __restrict__ ksm,
    const unsigned short* __restrict__ vt, const unsigned short* __restrict__ projp,
    const float* __restrict__ pos, unsigned short* __restrict__ ap) {
  int bid = blockIdx.x;
  int swz = (bid & 7) * 64 + (bid >> 3);   // bijective XCD swizzle: 2 heads per XCD
  int h = swz >> 5;
  int low5 = swz & 31;
  int qc = (h & 1) ? (31 - low5) : low5;   // complementary lengths for co-resident pair
  int q0 = qc * 64;
  int tid = threadIdx.x;
  int wid = tid >> 6, l = tid & 63;
  int w4 = wid & 3, jp = wid >> 2;         // q-group, j-half parity
  int joff = jp * 32;
  int c16 = l & 15, g = l >> 4;

  __shared__ __align__(16) char SMEMa[65536];
  // staging: K[b] at b*16384 ([64][256B]); V[b] at 32768 + b*16384 ([128][128B])

  int qrow = q0 + w4 * 16 + c16;
  int wmax = q0 + w4 * 16 + 15;
  bf16x8 qf[4];
  {
    const unsigned short* qb = q + (size_t)qrow * DEXP + h * DHEAD + g * 8;
    #pragma unroll
    for (int f = 0; f < 4; ++f) qf[f] = *reinterpret_cast<const bf16x8*>(qb + f * 32);
  }
  float pos_q = pos[h * SEQ + qrow];
  float m_run = -1e30f, l_run = 0.f;       // per-lane partial l (defer-psum)
  f32x4 z = {0.f, 0.f, 0.f, 0.f};
  f32x4 oacc[8];
  #pragma unroll
  for (int d = 0; d < 8; ++d) oacc[d] = z;

  int ntiles = qc + 1;
  int kch = tid & 15;
  int vch = tid & 7;

  auto STAGE = [&](int b, int t) {
    int j0 = t * 64;
    {
      int row = (tid >> 4);           // 0..31
      #pragma unroll
      for (int rr = 0; rr < 2; ++rr) {
        int r2 = rr * 32 + row;
        gload_lds16(ksm + (size_t)(j0 + r2) * DEXP + h * DHEAD + ((kch ^ (r2 & 7)) * 8),
                    SMEMa + b * 16384 + rr * 8192 + tid * 16);
      }
    }
    {
      int row = (tid >> 3);           // 0..63
      #pragma unroll
      for (int rr = 0; rr < 2; ++rr) {
        int r2 = rr * 64 + row;
        gload_lds16(vt + (size_t)(h * DHEAD + r2) * SEQ + j0 + ((vch ^ (r2 & 7)) * 8),
                    SMEMa + 32768 + b * 16384 + rr * 8192 + tid * 16);
      }
    }
  };

  STAGE(0, 0);
  __syncthreads();

  for (int t = 0; t < ntiles; ++t) {
    int cur = t & 1;
    if (t + 1 < ntiles) STAGE(cur ^ 1, t + 1);
    int j0 = t * 64;
    if (j0 + joff <= wmax) {   // wave-uniform skip of fully-masked half-tiles
      const char* Kb = SMEMa + cur * 16384;
      const char* Vb = SMEMa + 32768 + cur * 16384;
      f32x4 sT[2];
      #pragma unroll
      for (int sub = 0; sub < 2; ++sub) {
        sT[sub] = z;
        const char* kb = Kb + (joff + sub * 16 + c16) * 256;
        __builtin_amdgcn_s_setprio(1);
        #pragma unroll
        for (int f = 0; f < 4; ++f) {
          int cb = (f * 64 + g * 16) ^ ((c16 & 7) << 4);
          bf16x8 kf = *reinterpret_cast<const bf16x8*>(kb + cb);
          sT[sub] = __builtin_amdgcn_mfma_f32_16x16x32_bf16(kf, qf[f], sT[sub], 0, 0, 0);
        }
        __builtin_amdgcn_s_setprio(0);
      }
      float a[2][4], mt = -1e30f;
      #pragma unroll
      for (int sub = 0; sub < 2; ++sub) {
        float4 pjv = *reinterpret_cast<const float4*>(pos + h * SEQ + j0 + joff + sub * 16 + g * 4);
        float pj4[4] = { pjv.x, pjv.y, pjv.z, pjv.w };
        #pragma unroll
        for (int r = 0; r < 4; ++r) {
          int j = j0 + joff + sub * 16 + g * 4 + r;
          a[sub][r] = sT[sub][r] - pos_q + pj4[r] + (j > qrow ? -1e10f : 0.f);
          mt = fmaxf(mt, a[sub][r]);
        }
      }
      mt = fmaxf(mt, __shfl_xor(mt, 16, 64));
      mt = fmaxf(mt, __shfl_xor(mt, 32, 64));
      float mn = fmaxf(m_run, mt);
      if (mn - m_run > 8.f) {
        float alpha = __expf(m_run - mn);
        l_run *= alpha;
        #pragma unroll
        for (int d = 0; d < 8; ++d)
          #pragma unroll
          for (int r = 0; r < 4; ++r) oacc[d][r] *= alpha;
        m_run = mn;
      }
      float p[2][4];
      #pragma unroll
      for (int sub = 0; sub < 2; ++sub)
        #pragma unroll
        for (int r = 0; r < 4; ++r) { p[sub][r] = __expf(a[sub][r] - m_run); l_run += p[sub][r]; }
      unsigned long long pk0 = ((unsigned long long)pk2bf(p[0][2], p[0][3]) << 32)
                             |  pk2bf(p[0][0], p[0][1]);
      unsigned long long pk1 = ((unsigned long long)pk2bf(p[1][2], p[1][3]) << 32)
                             |  pk2bf(p[1][0], p[1][1]);
      int src = c16 + ((g & 1) << 5);
      unsigned long long t0 = __shfl(pk0, src, 64);
      unsigned long long t1 = __shfl(pk0, src + 16, 64);
      unsigned long long u0 = __shfl(pk1, src, 64);
      unsigned long long u1 = __shfl(pk1, src + 16, 64);
      union { unsigned long long u[2]; bf16x8 v; } pb;
      pb.u[0] = (g < 2) ? t0 : u0;
      pb.u[1] = (g < 2) ? t1 : u1;
      #pragma unroll
      for (int d = 0; d < 8; ++d) {
        const char* vb = Vb + (d * 16 + c16) * 128;
        int cb = (joff * 2 + g * 16) ^ ((c16 & 7) << 4);
        bf16x8 vf = *reinterpret_cast<const bf16x8*>(vb + cb);
        __builtin_amdgcn_s_setprio(1);
        oacc[d] = __builtin_amdgcn_mfma_f32_16x16x32_bf16(vf, pb.v, oacc[d], 0, 0, 0);
        __builtin_amdgcn_s_setprio(0);
      }
    }
    __syncthreads();
  }

  l_run += __shfl_xor(l_run, 16, 64);
  l_run += __shfl_xor(l_run, 32, 64);

  float* mbuf = (float*)SMEMa;                 // [4][2][16]
  float* obuf = (float*)(SMEMa + 1024);        // [4][16][132]
  if (jp == 0) {
    if (g == 0) {
      mbuf[(w4 * 2 + 0) * 16 + c16] = m_run;
      mbuf[(w4 * 2 + 1) * 16 + c16] = l_run;
    }
    #pragma unroll
    for (int d = 0; d < 8; ++d)
      #pragma unroll
      for (int r = 0; r < 4; ++r)
        obuf[(w4 * 16 + c16) * 132 + d * 16 + g * 4 + r] = oacc[d][r];
  }
  __syncthreads();
  if (jp == 1) {
    float m0 = mbuf[(w4 * 2 + 0) * 16 + c16];
    float l0 = mbuf[(w4 * 2 + 1) * 16 + c16];
    float M = fmaxf(m0, m_run);
    float s0 = __expf(m0 - M), s1 = __expf(m_run - M);
    float invl = 1.0f / (l0 * s0 + l_run * s1);
    #pragma unroll
    for (int d = 0; d < 8; ++d) {
      int nn = h * DHEAD + d * 16 + g * 4;
      ushort4 pv4 = *reinterpret_cast<const ushort4*>(projp + (size_t)qrow * DEXP + nn);
      ushort4 o4;
      unsigned short* pvp = reinterpret_cast<unsigned short*>(&pv4);
      unsigned short* op  = reinterpret_cast<unsigned short*>(&o4);
      #pragma unroll
      for (int r = 0; r < 4; ++r) {
        float o = (obuf[(w4 * 16 + c16) * 132 + d * 16 + g * 4 + r] * s0 + oacc[d][r] * s1) * invl;
        float pv = bf2f(pvp[r]);
        float si = pv / (1.f + __expf(-pv));
        op[r] = f2bf(si * o);
      }
      *reinterpret_cast<ushort4*>(ap + (size_t)qrow * DEXP + nn) = o4;
    }
  }
}

extern "C" void kernel_launch(void* const* d_in, const int* in_sizes, int n_in,
                              void* d_out, int out_size, void* d_ws, size_t ws_size,
                              hipStream_t stream) {
  const float* x         = (const float*)d_in[0];
  const float* W_in      = (const float*)d_in[1];
  const float* b_in      = (const float*)d_in[2];
  const float* in_ln_w   = (const float*)d_in[3];
  const float* in_ln_b   = (const float*)d_in[4];
  const float* W_out     = (const float*)d_in[5];
  const float* out_ln_w  = (const float*)d_in[6];
  const float* out_ln_b  = (const float*)d_in[7];
  const float* smearf    = (const float*)d_in[8];
  const float* log_scale = (const float*)d_in[9];
  float* out = (float*)d_out;

  char* ws = (char*)d_ws;
  size_t off = 0;
  auto alloc = [&](size_t bytes) -> void* {
    void* p = ws + off;
    off += (bytes + 255) & ~(size_t)255;
    return p;
  };
  unsigned short* xn     = (unsigned short*)alloc((size_t)SEQ * DMODEL * 2);
  unsigned short* winbf  = (unsigned short*)alloc((size_t)(4 * DEXP + NHEADS) * DMODEL * 2);
  unsigned short* woutbf = (unsigned short*)alloc((size_t)DMODEL * DEXP * 2);
  unsigned short* projq  = (unsigned short*)alloc((size_t)SEQ * DEXP * 2);
  unsigned short* projk  = (unsigned short*)alloc((size_t)SEQ * DEXP * 2);
  unsigned short* projp  = (unsigned short*)alloc((size_t)SEQ * DEXP * 2);
  unsigned short* vtb    = (unsigned short*)alloc((size_t)SEQ * DEXP * 2);
  unsigned short* ksm    = (unsigned short*)alloc((size_t)SEQ * DEXP * 2);
  unsigned short* apb    = (unsigned short*)alloc((size_t)SEQ * DEXP * 2);
  float* sig_y = (float*)alloc((size_t)NHEADS * SEQ * 4);
  float* posb  = (float*)alloc((size_t)NHEADS * SEQ * 4);
  float* outf  = (float*)alloc((size_t)2 * SEQ * DMODEL * 4);   // 2 split-K partials

  int nwin4  = (4 * DEXP + NHEADS) * DMODEL / 4;
  int nwout4 = DMODEL * DEXP / 4;
  castboth<<<(nwin4 + nwout4 + 255) / 256, 256, 0, stream>>>(
      W_in, winbf, nwin4, W_out, woutbf, nwout4);
  ln_kernel<<<SEQ, 256, 0, stream>>>(x, nullptr, in_ln_w, in_ln_b, xn, nullptr);
  gemm_lds<0><<<(SEQ / 128) * (4 * DEXP / 128), 256, 0, stream>>>(
      xn, winbf, SEQ, 4 * DEXP, DMODEL, b_in, log_scale, projq, projk, vtb, projp, nullptr);
  yproj<<<SEQ, 256, 0, stream>>>(xn, winbf, b_in, sig_y);
  scan_kernel<<<NHEADS, 256, 0, stream>>>(sig_y, posb);
  smear_kernel<<<(SEQ * DEXP + 255) / 256, 256, 0, stream>>>(projk, smearf, ksm);
  attn_kernel<<<512, 512, 0, stream>>>(projq, ksm, vtb, projp, posb, apb);
  gemm_lds<1><<<2 * (SEQ / 128) * (DMODEL / 128), 256, 0, stream>>>(
      apb, woutbf, SEQ, DMODEL, DEXP, nullptr, nullptr, nullptr, nullptr, nullptr, nullptr, outf);
  ln_kernel<<<SEQ, 256, 0, stream>>>(outf, outf + (size_t)SEQ * DMODEL, out_ln_w, out_ln_b,
                                     nullptr, out);
}